// Round 6
// baseline (1511.481 us; speedup 1.0000x reference)
//
#include <hip/hip_runtime.h>
#include <math.h>
#include <stdint.h>

#define N_NODES 20000
#define M_PAD 20032            // 313 * 64
#define N_EDGES 320000
#define N_GRAPHS 64
#define DIN 128
#define H 256
#define POOL_W 768

typedef __attribute__((ext_vector_type(8))) short bf16x8;   // 8 bf16 = 4 VGPRs
typedef __attribute__((ext_vector_type(4))) float f32x4;

__device__ __forceinline__ unsigned short f2bf(float f) {
    unsigned u = __builtin_bit_cast(unsigned, f);
    u += 0x7FFFu + ((u >> 16) & 1u);          // round-to-nearest-even
    return (unsigned short)(u >> 16);
}
__device__ __forceinline__ float bf2f(unsigned short u) {
    return __builtin_bit_cast(float, (unsigned)u << 16);
}

// ---------------------------------------------------------------------------
// CSR build
// ---------------------------------------------------------------------------
__global__ __launch_bounds__(256) void hist_kernel(const int* __restrict__ dst,
                                                   int* __restrict__ deg)
{
    const int i = blockIdx.x * 256 + threadIdx.x;
    if (i < N_EDGES) atomicAdd(deg + dst[i], 1);
}

__global__ __launch_bounds__(1024) void scan_kernel(const int* __restrict__ deg,
                                                    int* __restrict__ off)
{
    __shared__ int wsum[16];
    __shared__ int carry;
    const int tid = threadIdx.x, wave = tid >> 6, lane = tid & 63;
    if (tid == 0) carry = 0;
    __syncthreads();
    for (int base = 0; base < N_NODES; base += 1024) {
        const int i = base + tid;
        const int v = (i < N_NODES) ? deg[i] : 0;
        int s = v;
#pragma unroll
        for (int d = 1; d < 64; d <<= 1) {
            const int t = __shfl_up(s, d);
            if (lane >= d) s += t;
        }
        if (lane == 63) wsum[wave] = s;
        __syncthreads();
        if (wave == 0) {
            int t = (lane < 16) ? wsum[lane] : 0;
#pragma unroll
            for (int d = 1; d < 16; d <<= 1) {
                const int u = __shfl_up(t, d);
                if (lane >= d) t += u;
            }
            if (lane < 16) wsum[lane] = t;
        }
        __syncthreads();
        const int wbase = (wave == 0) ? 0 : wsum[wave - 1];
        if (i < N_NODES) off[i] = carry + wbase + s - v;
        const int tot = wsum[15];
        __syncthreads();
        if (tid == 0) carry += tot;
        __syncthreads();
    }
    if (tid == 0) off[N_NODES] = carry;
}

// scatter edge payload into dst-sorted order: src id + full 64B ea row
__global__ __launch_bounds__(256) void scatter_kernel(
    const int* __restrict__ src, const int* __restrict__ dst,
    const float4* __restrict__ ea4,
    int* __restrict__ cursor, int* __restrict__ srcS, float4* __restrict__ eaS4)
{
    const int e = blockIdx.x * 256 + threadIdx.x;
    if (e < N_EDGES) {
        const int p = atomicAdd(cursor + dst[e], 1);
        srcS[p] = src[e];
        const float4 a = ea4[e * 4 + 0], b = ea4[e * 4 + 1];
        const float4 c = ea4[e * 4 + 2], d = ea4[e * 4 + 3];
        eaS4[p * 4 + 0] = a; eaS4[p * 4 + 1] = b;
        eaS4[p * 4 + 2] = c; eaS4[p * 4 + 3] = d;
    }
}

__global__ void gstart_kernel(const int* __restrict__ batch, int* __restrict__ start)
{
    const int g = threadIdx.x;
    if (g > N_GRAPHS) return;
    if (g == N_GRAPHS) { start[N_GRAPHS] = N_NODES; return; }
    int lo = 0, hi = N_NODES;
    while (lo < hi) { const int mid = (lo + hi) >> 1; if (batch[mid] < g) lo = mid + 1; else hi = mid; }
    start[g] = lo;
}

// ---------------------------------------------------------------------------
__global__ __launch_bounds__(256) void cvt_bf(const float* __restrict__ w,
                                              unsigned short* __restrict__ o, int n4)
{
    const int i = blockIdx.x * 256 + threadIdx.x;
    if (i >= n4) return;
    const float4 v = ((const float4*)w)[i];
    ushort4 r;
    r.x = f2bf(v.x); r.y = f2bf(v.y); r.z = f2bf(v.z); r.w = f2bf(v.w);
    ((ushort4*)o)[i] = r;
}

// ---------------------------------------------------------------------------
// agg v4: one wave per node, CPL ch/lane, 2-deep pipelined edge loop.
// ea rows pre-sorted (sequential scalar loads); src pre-sorted.
// ---------------------------------------------------------------------------
template<int CPL>
struct EdgeSlot { float e[16]; ushort4 x; };

template<int IN, int CPL>
__device__ __forceinline__ void slot_load(EdgeSlot<CPL>& sl,
    const float* __restrict__ eaS, const int* __restrict__ srcS,
    const unsigned short* __restrict__ xb, int p, int c0)
{
    const int s = __builtin_amdgcn_readfirstlane(srcS[p]);
    const float* er = eaS + (size_t)p * 16;
#pragma unroll
    for (int k = 0; k < 16; ++k) sl.e[k] = er[k];
    if (CPL == 4) {
        sl.x = *(const ushort4*)(xb + (size_t)s * IN + c0);
    } else {
        const ushort2 t2 = *(const ushort2*)(xb + (size_t)s * IN + c0);
        sl.x.x = t2.x; sl.x.y = t2.y;
    }
}

template<int CPL>
__device__ __forceinline__ void slot_compute(const EdgeSlot<CPL>& sl,
    const float (&w)[CPL][16], const float (&bias)[CPL], float (&acc)[CPL])
{
    float m[CPL];
#pragma unroll
    for (int j = 0; j < CPL; ++j) m[j] = bias[j];
#pragma unroll
    for (int k = 0; k < 16; ++k)
#pragma unroll
        for (int j = 0; j < CPL; ++j) m[j] = fmaf(sl.e[k], w[j][k], m[j]);
#pragma unroll
    for (int j = 0; j < CPL; ++j) {
        const float v = m[j] + bf2f((&sl.x.x)[j]);
        acc[j] += fmaxf(v, 0.0f);
    }
}

template<int IN>
__global__ __launch_bounds__(256, 8) void agg4(
    const unsigned short* __restrict__ xb,   // [M_PAD, IN] bf16
    const float* __restrict__ eaS,           // [E,16] sorted by dst
    const int* __restrict__ srcS,            // [E] sorted by dst
    const int* __restrict__ off,             // [N+1]
    const float* __restrict__ We, const float* __restrict__ be,
    unsigned short* __restrict__ out)        // [M_PAD, IN] bf16
{
    constexpr int CPL = IN / 64;
    const int lane = threadIdx.x & 63;
    const int node = blockIdx.x * 4 + (threadIdx.x >> 6);
    if (node >= N_NODES) return;
    const int c0 = lane * CPL;

    float w[CPL][16], bias[CPL], acc[CPL];
#pragma unroll
    for (int j = 0; j < CPL; ++j) {
        bias[j] = be[c0 + j];
        acc[j]  = 0.0f;
#pragma unroll
        for (int k = 0; k < 16; ++k) w[j][k] = We[(c0 + j) * 16 + k];
    }

    const int p0 = __builtin_amdgcn_readfirstlane(off[node]);
    const int p1 = __builtin_amdgcn_readfirstlane(off[node + 1]);
    const int n  = p1 - p0;

    EdgeSlot<CPL> s0, s1;
    if (n >= 1) slot_load<IN, CPL>(s0, eaS, srcS, xb, p0, c0);
    if (n >= 2) slot_load<IN, CPL>(s1, eaS, srcS, xb, p0 + 1, c0);

    int p = p0;
    while (p + 2 <= p1) {
        slot_compute<CPL>(s0, w, bias, acc);
        if (p + 2 < p1) slot_load<IN, CPL>(s0, eaS, srcS, xb, p + 2, c0);
        slot_compute<CPL>(s1, w, bias, acc);
        if (p + 3 < p1) slot_load<IN, CPL>(s1, eaS, srcS, xb, p + 3, c0);
        p += 2;
    }
    if (p < p1) slot_compute<CPL>(s0, w, bias, acc);

    if (CPL == 4) {
        const ushort4 xs = *(const ushort4*)(xb + (size_t)node * IN + c0);
        ushort4 o;
#pragma unroll
        for (int j = 0; j < 4; ++j) (&o.x)[j] = f2bf(bf2f((&xs.x)[j]) + acc[j]);
        *(ushort4*)(out + (size_t)node * IN + c0) = o;
    } else {
        const ushort2 xs = *(const ushort2*)(xb + (size_t)node * IN + c0);
        ushort2 o;
        o.x = f2bf(bf2f(xs.x) + acc[0]);
        o.y = f2bf(bf2f(xs.y) + acc[1]);
        *(ushort2*)(out + (size_t)node * IN + c0) = o;
    }
}

// ---------------------------------------------------------------------------
// Fused layer MLP v2: H = relu( relu(BN(U@Wa.T)) @ Wb.T + bb ), bf16 MFMA.
// Block = 64 rows x 256 cols, 4 waves in 2x2: wave (mw,nw) owns 32 rows x
// 128 cols = 2m x 8n tiles -> 16 MFMA per 10 ds_read_b128 (was 17).
// ---------------------------------------------------------------------------
template<int K1>
__global__ __launch_bounds__(256, 2) void gine_mlp(
    const unsigned short* __restrict__ U,    // [M_PAD, K1]
    const unsigned short* __restrict__ Wa,   // [256, K1]
    const float* __restrict__ ba, const float* __restrict__ gsc, const float* __restrict__ bsh,
    const unsigned short* __restrict__ Wb,   // [256, 256]
    const float* __restrict__ bb,
    unsigned short* __restrict__ Hout)       // [M_PAD, 256]
{
    __shared__ unsigned short Sm[33280];     // 65 KB
    unsigned short* AS = Sm;                 // phase1 A-stage  [4096]
    unsigned short* BS = Sm + 4096;          // phase1 B-stage  [16384]
    unsigned short* T  = Sm;                 // phase2 A (64 x 264)
    unsigned short* B2 = Sm + 16896;         // phase2 B-stage  [16384]

    const int t  = threadIdx.x;
    const int w  = t >> 6, lane = t & 63;
    const int lm = lane & 15, lq = lane >> 4;
    const int bm = blockIdx.x * 64;
    const int mw = w & 1, nw = w >> 1;

    f32x4 acc[2][8];
#pragma unroll
    for (int i = 0; i < 2; ++i)
#pragma unroll
        for (int j = 0; j < 8; ++j) acc[i][j] = (f32x4){0.f, 0.f, 0.f, 0.f};

    // ---------------- phase 1: U @ Wa.T -----------------
    const unsigned short* Ag = U + (size_t)(bm + w * 16 + lm) * K1 + lq * 8;
    const unsigned short* Bg[4];
#pragma unroll
    for (int j = 0; j < 4; ++j)
        Bg[j] = Wa + (size_t)((w * 4 + j) * 16 + lm) * K1 + lq * 8;

    unsigned short* ASw = AS + w * 1024 + lane * 8;
    unsigned short* BSw = BS + (w * 4) * 1024 + lane * 8;

    uint4 ra0 = *(const uint4*)Ag, ra1 = *(const uint4*)(Ag + 32);
    uint4 rb0[4], rb1[4];
#pragma unroll
    for (int j = 0; j < 4; ++j) { rb0[j] = *(const uint4*)Bg[j]; rb1[j] = *(const uint4*)(Bg[j] + 32); }

    for (int k0 = 0; k0 < K1; k0 += 64) {
        __syncthreads();
        *(uint4*)ASw = ra0; *(uint4*)(ASw + 512) = ra1;
#pragma unroll
        for (int j = 0; j < 4; ++j) {
            *(uint4*)(BSw + j * 1024) = rb0[j];
            *(uint4*)(BSw + j * 1024 + 512) = rb1[j];
        }
        if (k0 + 64 < K1) {
            Ag += 64;
            ra0 = *(const uint4*)Ag; ra1 = *(const uint4*)(Ag + 32);
#pragma unroll
            for (int j = 0; j < 4; ++j) {
                Bg[j] += 64;
                rb0[j] = *(const uint4*)Bg[j]; rb1[j] = *(const uint4*)(Bg[j] + 32);
            }
        }
        __syncthreads();
#pragma unroll
        for (int kk = 0; kk < 2; ++kk) {
            const bf16x8 a0 = *(const bf16x8*)(AS + (2 * mw + 0) * 1024 + lane * 8 + kk * 512);
            const bf16x8 a1 = *(const bf16x8*)(AS + (2 * mw + 1) * 1024 + lane * 8 + kk * 512);
#pragma unroll
            for (int j = 0; j < 8; ++j) {
                const bf16x8 b = *(const bf16x8*)(BS + (nw * 8 + j) * 1024 + lane * 8 + kk * 512);
                acc[0][j] = __builtin_amdgcn_mfma_f32_16x16x32_bf16(a0, b, acc[0][j], 0, 0, 0);
                acc[1][j] = __builtin_amdgcn_mfma_f32_16x16x32_bf16(a1, b, acc[1][j], 0, 0, 0);
            }
        }
    }

    __syncthreads();                          // AS/BS dead; safe to overwrite with T
    const float inv = rsqrtf(1.0f + 1e-5f);
#pragma unroll
    for (int mi = 0; mi < 2; ++mi) {
#pragma unroll
        for (int j = 0; j < 8; ++j) {
            const int col = (nw * 8 + j) * 16 + lm;
            const float bc = ba[col], gc = gsc[col], sc = bsh[col];
#pragma unroll
            for (int r = 0; r < 4; ++r) {
                const int lr = (2 * mw + mi) * 16 + lq * 4 + r;
                const float v = fmaxf((acc[mi][j][r] + bc) * inv * gc + sc, 0.0f);
                T[lr * 264 + col] = f2bf(v);
            }
            acc[mi][j] = (f32x4){0.f, 0.f, 0.f, 0.f};
        }
    }

    // ---------------- phase 2: T @ Wb.T -----------------
    const unsigned short* Cg[4];
#pragma unroll
    for (int j = 0; j < 4; ++j)
        Cg[j] = Wb + (size_t)((w * 4 + j) * 16 + lm) * H + lq * 8;
#pragma unroll
    for (int j = 0; j < 4; ++j) { rb0[j] = *(const uint4*)Cg[j]; rb1[j] = *(const uint4*)(Cg[j] + 32); }
    unsigned short* B2w = B2 + (w * 4) * 1024 + lane * 8;

    for (int k0 = 0; k0 < H; k0 += 64) {
        __syncthreads();                      // T writes visible / prev B2 reads done
#pragma unroll
        for (int j = 0; j < 4; ++j) {
            *(uint4*)(B2w + j * 1024) = rb0[j];
            *(uint4*)(B2w + j * 1024 + 512) = rb1[j];
        }
        if (k0 + 64 < H) {
#pragma unroll
            for (int j = 0; j < 4; ++j) {
                Cg[j] += 64;
                rb0[j] = *(const uint4*)Cg[j]; rb1[j] = *(const uint4*)(Cg[j] + 32);
            }
        }
        __syncthreads();
#pragma unroll
        for (int kk = 0; kk < 2; ++kk) {
            const bf16x8 a0 = *(const bf16x8*)(T + ((2 * mw + 0) * 16 + lm) * 264 + k0 + kk * 32 + lq * 8);
            const bf16x8 a1 = *(const bf16x8*)(T + ((2 * mw + 1) * 16 + lm) * 264 + k0 + kk * 32 + lq * 8);
#pragma unroll
            for (int j = 0; j < 8; ++j) {
                const bf16x8 b = *(const bf16x8*)(B2 + (nw * 8 + j) * 1024 + lane * 8 + kk * 512);
                acc[0][j] = __builtin_amdgcn_mfma_f32_16x16x32_bf16(a0, b, acc[0][j], 0, 0, 0);
                acc[1][j] = __builtin_amdgcn_mfma_f32_16x16x32_bf16(a1, b, acc[1][j], 0, 0, 0);
            }
        }
    }

#pragma unroll
    for (int mi = 0; mi < 2; ++mi) {
#pragma unroll
        for (int j = 0; j < 8; ++j) {
            const int col = (nw * 8 + j) * 16 + lm;
            const float bc = bb[col];
#pragma unroll
            for (int r = 0; r < 4; ++r) {
                const int row = bm + (2 * mw + mi) * 16 + lq * 4 + r;
                if (row < N_NODES)
                    Hout[(size_t)row * H + col] = f2bf(fmaxf(acc[mi][j][r] + bc, 0.0f));
            }
        }
    }
}

// ---------------------------------------------------------------------------
__global__ __launch_bounds__(256) void pool_kernel(
    const unsigned short* __restrict__ h1, const unsigned short* __restrict__ h2,
    const unsigned short* __restrict__ h3, const int* __restrict__ start,
    float* __restrict__ pool)
{
    const int g = blockIdx.x & 63, layer = blockIdx.x >> 6;
    const unsigned short* h = (layer == 0) ? h1 : (layer == 1) ? h2 : h3;
    const int r0 = start[g], r1 = start[g + 1];
    const int c = threadIdx.x;
    float s0 = 0.f, s1 = 0.f, s2 = 0.f, s3 = 0.f;
    int r = r0;
    for (; r + 4 <= r1; r += 4) {
        s0 += bf2f(h[(size_t)(r + 0) * H + c]);
        s1 += bf2f(h[(size_t)(r + 1) * H + c]);
        s2 += bf2f(h[(size_t)(r + 2) * H + c]);
        s3 += bf2f(h[(size_t)(r + 3) * H + c]);
    }
    for (; r < r1; ++r) s0 += bf2f(h[(size_t)r * H + c]);
    pool[(size_t)g * POOL_W + layer * 256 + c] =
        (s0 + s1 + s2 + s3) / fmaxf((float)(r1 - r0), 1.0f);
}

// ---------------------------------------------------------------------------
__global__ __launch_bounds__(256) void final_kernel(
    const float* __restrict__ pool,
    const float* __restrict__ L1w, const float* __restrict__ L1b,
    const float* __restrict__ L2w, const float* __restrict__ L2b,
    float* __restrict__ out)
{
    const int g = blockIdx.x;
    __shared__ float p[POOL_W];
    __shared__ float f1[POOL_W];
    __shared__ float red[4];

    for (int i = threadIdx.x; i < POOL_W; i += 256)
        p[i] = pool[(size_t)g * POOL_W + i];
    __syncthreads();

    for (int r = 0; r < 3; ++r) {
        const int o = r * 256 + threadIdx.x;
        float acc = L1b[o];
        const float4* wrow = (const float4*)(L1w + (size_t)o * POOL_W);
        for (int k4 = 0; k4 < POOL_W / 4; ++k4) {
            const float4 w4 = wrow[k4];
            acc += w4.x * p[k4 * 4 + 0] + w4.y * p[k4 * 4 + 1]
                 + w4.z * p[k4 * 4 + 2] + w4.w * p[k4 * 4 + 3];
        }
        f1[o] = fmaxf(acc, 0.0f);
    }
    __syncthreads();

    float part = 0.0f;
    for (int i = threadIdx.x; i < POOL_W; i += 256) part += f1[i] * L2w[i];
#pragma unroll
    for (int off = 32; off > 0; off >>= 1) part += __shfl_down(part, off);
    if ((threadIdx.x & 63) == 0) red[threadIdx.x >> 6] = part;
    __syncthreads();
    if (threadIdx.x == 0) {
        const float s = red[0] + red[1] + red[2] + red[3] + L2b[0];
        out[g] = 1.0f / (1.0f + expf(-s));
    }
}

// ---------------------------------------------------------------------------
extern "C" void kernel_launch(void* const* d_in, const int* in_sizes, int n_in,
                              void* d_out, int out_size, void* d_ws, size_t ws_size,
                              hipStream_t stream)
{
    const float* x     = (const float*)d_in[0];
    const float* ea    = (const float*)d_in[1];
    const int*   src   = (const int*)d_in[2];
    const int*   dst   = (const int*)d_in[3];
    const int*   batch = (const int*)d_in[4];

    const float* We[3]; const float* be[3]; const float* Wa[3]; const float* ba[3];
    const float* gg[3]; const float* bt[3]; const float* Wb[3]; const float* bb[3];
    for (int l = 0; l < 3; ++l) {
        const int o = 5 + 8 * l;
        We[l] = (const float*)d_in[o + 0]; be[l] = (const float*)d_in[o + 1];
        Wa[l] = (const float*)d_in[o + 2]; ba[l] = (const float*)d_in[o + 3];
        gg[l] = (const float*)d_in[o + 4]; bt[l] = (const float*)d_in[o + 5];
        Wb[l] = (const float*)d_in[o + 6]; bb[l] = (const float*)d_in[o + 7];
    }
    const float* L1w = (const float*)d_in[29];
    const float* L1b = (const float*)d_in[30];
    const float* L2w = (const float*)d_in[31];
    const float* L2b = (const float*)d_in[32];

    // ---- workspace layout ----
    float* pool   = (float*)d_ws;                              // 64*768
    int*   deg    = (int*)(pool + (size_t)N_GRAPHS * POOL_W);  // N
    int*   off    = deg + N_NODES;                             // N+1
    int*   cursor = off + N_NODES + 1;                         // N
    int*   start  = cursor + N_NODES;                          // 72
    int*   srcS   = start + 72;                                // E
    float* eaS    = (float*)((((uintptr_t)(srcS + N_EDGES)) + 63) & ~(uintptr_t)63);  // E*16
    unsigned short* xb = (unsigned short*)(eaS + (size_t)N_EDGES * 16);
    unsigned short* u  = xb + (size_t)M_PAD * DIN;             // [M_PAD,256] (layer1 uses 128)
    unsigned short* h1 = u  + (size_t)M_PAD * H;
    unsigned short* h2 = h1 + (size_t)M_PAD * H;
    unsigned short* h3 = h2 + (size_t)M_PAD * H;
    unsigned short* wbf[6];
    wbf[0] = h3 + (size_t)M_PAD * H;                           // Wa1 [256,128]
    wbf[1] = wbf[0] + H * DIN;
    for (int i = 2; i < 6; ++i) wbf[i] = wbf[i - 1] + H * H;

    hipMemsetAsync(deg, 0, (size_t)N_NODES * sizeof(int), stream);

    // converts
    cvt_bf<<<(N_NODES * DIN / 4 + 255) / 256, 256, 0, stream>>>(x, xb, N_NODES * DIN / 4);
    for (int l = 0; l < 3; ++l) {
        const int ka = (l == 0) ? DIN : H;
        cvt_bf<<<(H * ka / 4 + 255) / 256, 256, 0, stream>>>(Wa[l], wbf[2 * l], H * ka / 4);
        cvt_bf<<<(H * H  / 4 + 255) / 256, 256, 0, stream>>>(Wb[l], wbf[2 * l + 1], H * H / 4);
    }

    // CSR + graph boundaries
    hist_kernel<<<(N_EDGES + 255) / 256, 256, 0, stream>>>(dst, deg);
    scan_kernel<<<1, 1024, 0, stream>>>(deg, off);
    hipMemcpyAsync(cursor, off, (size_t)N_NODES * sizeof(int),
                   hipMemcpyDeviceToDevice, stream);
    scatter_kernel<<<(N_EDGES + 255) / 256, 256, 0, stream>>>(src, dst, (const float4*)ea,
                                                              cursor, srcS, (float4*)eaS);
    gstart_kernel<<<1, 128, 0, stream>>>(batch, start);

    const int agrid = (N_NODES + 3) / 4;
    const int mgrid = M_PAD / 64;   // 313

    // ---- layer 1 (in=128) ----
    agg4<DIN><<<agrid, 256, 0, stream>>>(xb, eaS, srcS, off, We[0], be[0], u);
    gine_mlp<DIN><<<mgrid, 256, 0, stream>>>(u, wbf[0], ba[0], gg[0], bt[0], wbf[1], bb[0], h1);
    // ---- layer 2 ----
    agg4<H><<<agrid, 256, 0, stream>>>(h1, eaS, srcS, off, We[1], be[1], u);
    gine_mlp<H><<<mgrid, 256, 0, stream>>>(u, wbf[2], ba[1], gg[1], bt[1], wbf[3], bb[1], h2);
    // ---- layer 3 ----
    agg4<H><<<agrid, 256, 0, stream>>>(h2, eaS, srcS, off, We[2], be[2], u);
    gine_mlp<H><<<mgrid, 256, 0, stream>>>(u, wbf[4], ba[2], gg[2], bt[2], wbf[5], bb[2], h3);

    // pooling + head
    pool_kernel<<<3 * N_GRAPHS, 256, 0, stream>>>(h1, h2, h3, start, pool);
    final_kernel<<<N_GRAPHS, 256, 0, stream>>>(pool, L1w, L1b, L2w, L2b, (float*)d_out);
}

// Round 7
// 683.553 us; speedup vs baseline: 2.2112x; 2.2112x over previous
//
#include <hip/hip_runtime.h>
#include <math.h>
#include <stdint.h>

#define N_NODES 20000
#define M_PAD 20032            // 313 * 64
#define N_EDGES 320000
#define N_GRAPHS 64
#define DIN 128
#define H 256
#define POOL_W 768

typedef __attribute__((ext_vector_type(8))) short bf16x8;   // 8 bf16 = 4 VGPRs
typedef __attribute__((ext_vector_type(4))) float f32x4;

__device__ __forceinline__ unsigned short f2bf(float f) {
    unsigned u = __builtin_bit_cast(unsigned, f);
    u += 0x7FFFu + ((u >> 16) & 1u);          // round-to-nearest-even
    return (unsigned short)(u >> 16);
}
__device__ __forceinline__ float bf2f(unsigned short u) {
    return __builtin_bit_cast(float, (unsigned)u << 16);
}

// ---------------------------------------------------------------------------
// CSR build
// ---------------------------------------------------------------------------
__global__ __launch_bounds__(256) void hist_kernel(const int* __restrict__ dst,
                                                   int* __restrict__ deg)
{
    const int i = blockIdx.x * 256 + threadIdx.x;
    if (i < N_EDGES) atomicAdd(deg + dst[i], 1);
}

__global__ __launch_bounds__(1024) void scan_kernel(const int* __restrict__ deg,
                                                    int* __restrict__ off)
{
    __shared__ int wsum[16];
    __shared__ int carry;
    const int tid = threadIdx.x, wave = tid >> 6, lane = tid & 63;
    if (tid == 0) carry = 0;
    __syncthreads();
    for (int base = 0; base < N_NODES; base += 1024) {
        const int i = base + tid;
        const int v = (i < N_NODES) ? deg[i] : 0;
        int s = v;
#pragma unroll
        for (int d = 1; d < 64; d <<= 1) {
            const int t = __shfl_up(s, d);
            if (lane >= d) s += t;
        }
        if (lane == 63) wsum[wave] = s;
        __syncthreads();
        if (wave == 0) {
            int t = (lane < 16) ? wsum[lane] : 0;
#pragma unroll
            for (int d = 1; d < 16; d <<= 1) {
                const int u = __shfl_up(t, d);
                if (lane >= d) t += u;
            }
            if (lane < 16) wsum[lane] = t;
        }
        __syncthreads();
        const int wbase = (wave == 0) ? 0 : wsum[wave - 1];
        if (i < N_NODES) off[i] = carry + wbase + s - v;
        const int tot = wsum[15];
        __syncthreads();
        if (tid == 0) carry += tot;
        __syncthreads();
    }
    if (tid == 0) off[N_NODES] = carry;
}

// scatter edge payload into dst-sorted order: src id + full 64B ea row
__global__ __launch_bounds__(256) void scatter_kernel(
    const int* __restrict__ src, const int* __restrict__ dst,
    const float4* __restrict__ ea4,
    int* __restrict__ cursor, int* __restrict__ srcS, float4* __restrict__ eaS4)
{
    const int e = blockIdx.x * 256 + threadIdx.x;
    if (e < N_EDGES) {
        const int p = atomicAdd(cursor + dst[e], 1);
        srcS[p] = src[e];
        const float4 a = ea4[e * 4 + 0], b = ea4[e * 4 + 1];
        const float4 c = ea4[e * 4 + 2], d = ea4[e * 4 + 3];
        eaS4[p * 4 + 0] = a; eaS4[p * 4 + 1] = b;
        eaS4[p * 4 + 2] = c; eaS4[p * 4 + 3] = d;
    }
}

__global__ void gstart_kernel(const int* __restrict__ batch, int* __restrict__ start)
{
    const int g = threadIdx.x;
    if (g > N_GRAPHS) return;
    if (g == N_GRAPHS) { start[N_GRAPHS] = N_NODES; return; }
    int lo = 0, hi = N_NODES;
    while (lo < hi) { const int mid = (lo + hi) >> 1; if (batch[mid] < g) lo = mid + 1; else hi = mid; }
    start[g] = lo;
}

// ---------------------------------------------------------------------------
__global__ __launch_bounds__(256) void cvt_bf(const float* __restrict__ w,
                                              unsigned short* __restrict__ o, int n4)
{
    const int i = blockIdx.x * 256 + threadIdx.x;
    if (i >= n4) return;
    const float4 v = ((const float4*)w)[i];
    ushort4 r;
    r.x = f2bf(v.x); r.y = f2bf(v.y); r.z = f2bf(v.z); r.w = f2bf(v.w);
    ((ushort4*)o)[i] = r;
}

// ---------------------------------------------------------------------------
// agg v5 = R5's proven agg3 structure + dst-sorted eaS (sequential scalar
// ea loads addressed by the uniform loop index; no index indirection).
// out[v] = bf16( x[v] + sum_e relu(x[src] + ea@We.T + be) )
// ---------------------------------------------------------------------------
template<int IN>
__global__ __launch_bounds__(256, 4) void agg5(
    const unsigned short* __restrict__ xb,   // [M_PAD, IN] bf16
    const float* __restrict__ eaS,           // [E,16] fp32, dst-sorted
    const int* __restrict__ srcS,            // [E] dst-sorted
    const int* __restrict__ off,             // [N+1]
    const float* __restrict__ We, const float* __restrict__ be,
    unsigned short* __restrict__ out)        // [M_PAD, IN] bf16
{
    constexpr int CPL = IN / 64;             // 2 (layer1) or 4
    const int lane = threadIdx.x & 63;
    const int node = blockIdx.x * 4 + (threadIdx.x >> 6);
    if (node >= N_NODES) return;
    const int c0 = lane * CPL;

    float w[CPL][16], bias[CPL], acc[CPL];
#pragma unroll
    for (int j = 0; j < CPL; ++j) {
        bias[j] = be[c0 + j];
        acc[j]  = 0.0f;
#pragma unroll
        for (int k = 0; k < 16; ++k) w[j][k] = We[(c0 + j) * 16 + k];
    }

    const int p0 = __builtin_amdgcn_readfirstlane(off[node]);
    const int p1 = __builtin_amdgcn_readfirstlane(off[node + 1]);

    float  en[16];
    ushort4 xn = {0, 0, 0, 0};
    if (p0 < p1) {
        const int s = __builtin_amdgcn_readfirstlane(srcS[p0]);
        const float* er = eaS + (size_t)p0 * 16;
#pragma unroll
        for (int k = 0; k < 16; ++k) en[k] = er[k];
        if (CPL == 4) xn = *(const ushort4*)(xb + (size_t)s * IN + c0);
        else { const ushort2 t2 = *(const ushort2*)(xb + (size_t)s * IN + c0); xn.x = t2.x; xn.y = t2.y; }
    }

    for (int p = p0; p < p1; ++p) {
        float ec[16];
#pragma unroll
        for (int k = 0; k < 16; ++k) ec[k] = en[k];
        const ushort4 xc = xn;
        if (p + 1 < p1) {
            const int s = __builtin_amdgcn_readfirstlane(srcS[p + 1]);
            const float* er = eaS + (size_t)(p + 1) * 16;
#pragma unroll
            for (int k = 0; k < 16; ++k) en[k] = er[k];
            if (CPL == 4) xn = *(const ushort4*)(xb + (size_t)s * IN + c0);
            else { const ushort2 t2 = *(const ushort2*)(xb + (size_t)s * IN + c0); xn.x = t2.x; xn.y = t2.y; }
        }
        float m[CPL];
#pragma unroll
        for (int j = 0; j < CPL; ++j) m[j] = bias[j];
#pragma unroll
        for (int k = 0; k < 16; ++k)
#pragma unroll
            for (int j = 0; j < CPL; ++j) m[j] = fmaf(ec[k], w[j][k], m[j]);
#pragma unroll
        for (int j = 0; j < CPL; ++j) {
            const float v = m[j] + bf2f((&xc.x)[j]);
            acc[j] += fmaxf(v, 0.0f);
        }
    }

    if (CPL == 4) {
        const ushort4 xs = *(const ushort4*)(xb + (size_t)node * IN + c0);
        ushort4 o;
#pragma unroll
        for (int j = 0; j < 4; ++j) (&o.x)[j] = f2bf(bf2f((&xs.x)[j]) + acc[j]);
        *(ushort4*)(out + (size_t)node * IN + c0) = o;
    } else {
        const ushort2 xs = *(const ushort2*)(xb + (size_t)node * IN + c0);
        ushort2 o;
        o.x = f2bf(bf2f(xs.x) + acc[0]);
        o.y = f2bf(bf2f(xs.y) + acc[1]);
        *(ushort2*)(out + (size_t)node * IN + c0) = o;
    }
}

// ---------------------------------------------------------------------------
// Fused layer MLP v2: H = relu( relu(BN(U@Wa.T)) @ Wb.T + bb ), bf16 MFMA.
// Block = 64 rows x 256 cols, 4 waves in 2x2: wave (mw,nw) owns 32 rows x
// 128 cols = 2m x 8n tiles -> 16 MFMA per 10 ds_read_b128.
// ---------------------------------------------------------------------------
template<int K1>
__global__ __launch_bounds__(256, 2) void gine_mlp(
    const unsigned short* __restrict__ U,    // [M_PAD, K1]
    const unsigned short* __restrict__ Wa,   // [256, K1]
    const float* __restrict__ ba, const float* __restrict__ gsc, const float* __restrict__ bsh,
    const unsigned short* __restrict__ Wb,   // [256, 256]
    const float* __restrict__ bb,
    unsigned short* __restrict__ Hout)       // [M_PAD, 256]
{
    __shared__ unsigned short Sm[33280];     // 65 KB
    unsigned short* AS = Sm;                 // phase1 A-stage  [4096]
    unsigned short* BS = Sm + 4096;          // phase1 B-stage  [16384]
    unsigned short* T  = Sm;                 // phase2 A (64 x 264)
    unsigned short* B2 = Sm + 16896;         // phase2 B-stage  [16384]

    const int t  = threadIdx.x;
    const int w  = t >> 6, lane = t & 63;
    const int lm = lane & 15, lq = lane >> 4;
    const int bm = blockIdx.x * 64;
    const int mw = w & 1, nw = w >> 1;

    f32x4 acc[2][8];
#pragma unroll
    for (int i = 0; i < 2; ++i)
#pragma unroll
        for (int j = 0; j < 8; ++j) acc[i][j] = (f32x4){0.f, 0.f, 0.f, 0.f};

    // ---------------- phase 1: U @ Wa.T -----------------
    const unsigned short* Ag = U + (size_t)(bm + w * 16 + lm) * K1 + lq * 8;
    const unsigned short* Bg[4];
#pragma unroll
    for (int j = 0; j < 4; ++j)
        Bg[j] = Wa + (size_t)((w * 4 + j) * 16 + lm) * K1 + lq * 8;

    unsigned short* ASw = AS + w * 1024 + lane * 8;
    unsigned short* BSw = BS + (w * 4) * 1024 + lane * 8;

    uint4 ra0 = *(const uint4*)Ag, ra1 = *(const uint4*)(Ag + 32);
    uint4 rb0[4], rb1[4];
#pragma unroll
    for (int j = 0; j < 4; ++j) { rb0[j] = *(const uint4*)Bg[j]; rb1[j] = *(const uint4*)(Bg[j] + 32); }

    for (int k0 = 0; k0 < K1; k0 += 64) {
        __syncthreads();
        *(uint4*)ASw = ra0; *(uint4*)(ASw + 512) = ra1;
#pragma unroll
        for (int j = 0; j < 4; ++j) {
            *(uint4*)(BSw + j * 1024) = rb0[j];
            *(uint4*)(BSw + j * 1024 + 512) = rb1[j];
        }
        if (k0 + 64 < K1) {
            Ag += 64;
            ra0 = *(const uint4*)Ag; ra1 = *(const uint4*)(Ag + 32);
#pragma unroll
            for (int j = 0; j < 4; ++j) {
                Bg[j] += 64;
                rb0[j] = *(const uint4*)Bg[j]; rb1[j] = *(const uint4*)(Bg[j] + 32);
            }
        }
        __syncthreads();
#pragma unroll
        for (int kk = 0; kk < 2; ++kk) {
            const bf16x8 a0 = *(const bf16x8*)(AS + (2 * mw + 0) * 1024 + lane * 8 + kk * 512);
            const bf16x8 a1 = *(const bf16x8*)(AS + (2 * mw + 1) * 1024 + lane * 8 + kk * 512);
#pragma unroll
            for (int j = 0; j < 8; ++j) {
                const bf16x8 b = *(const bf16x8*)(BS + (nw * 8 + j) * 1024 + lane * 8 + kk * 512);
                acc[0][j] = __builtin_amdgcn_mfma_f32_16x16x32_bf16(a0, b, acc[0][j], 0, 0, 0);
                acc[1][j] = __builtin_amdgcn_mfma_f32_16x16x32_bf16(a1, b, acc[1][j], 0, 0, 0);
            }
        }
    }

    __syncthreads();                          // AS/BS dead; safe to overwrite with T
    const float inv = rsqrtf(1.0f + 1e-5f);
#pragma unroll
    for (int mi = 0; mi < 2; ++mi) {
#pragma unroll
        for (int j = 0; j < 8; ++j) {
            const int col = (nw * 8 + j) * 16 + lm;
            const float bc = ba[col], gc = gsc[col], sc = bsh[col];
#pragma unroll
            for (int r = 0; r < 4; ++r) {
                const int lr = (2 * mw + mi) * 16 + lq * 4 + r;
                const float v = fmaxf((acc[mi][j][r] + bc) * inv * gc + sc, 0.0f);
                T[lr * 264 + col] = f2bf(v);
            }
            acc[mi][j] = (f32x4){0.f, 0.f, 0.f, 0.f};
        }
    }

    // ---------------- phase 2: T @ Wb.T -----------------
    const unsigned short* Cg[4];
#pragma unroll
    for (int j = 0; j < 4; ++j)
        Cg[j] = Wb + (size_t)((w * 4 + j) * 16 + lm) * H + lq * 8;
#pragma unroll
    for (int j = 0; j < 4; ++j) { rb0[j] = *(const uint4*)Cg[j]; rb1[j] = *(const uint4*)(Cg[j] + 32); }
    unsigned short* B2w = B2 + (w * 4) * 1024 + lane * 8;

    for (int k0 = 0; k0 < H; k0 += 64) {
        __syncthreads();                      // T writes visible / prev B2 reads done
#pragma unroll
        for (int j = 0; j < 4; ++j) {
            *(uint4*)(B2w + j * 1024) = rb0[j];
            *(uint4*)(B2w + j * 1024 + 512) = rb1[j];
        }
        if (k0 + 64 < H) {
#pragma unroll
            for (int j = 0; j < 4; ++j) {
                Cg[j] += 64;
                rb0[j] = *(const uint4*)Cg[j]; rb1[j] = *(const uint4*)(Cg[j] + 32);
            }
        }
        __syncthreads();
#pragma unroll
        for (int kk = 0; kk < 2; ++kk) {
            const bf16x8 a0 = *(const bf16x8*)(T + ((2 * mw + 0) * 16 + lm) * 264 + k0 + kk * 32 + lq * 8);
            const bf16x8 a1 = *(const bf16x8*)(T + ((2 * mw + 1) * 16 + lm) * 264 + k0 + kk * 32 + lq * 8);
#pragma unroll
            for (int j = 0; j < 8; ++j) {
                const bf16x8 b = *(const bf16x8*)(B2 + (nw * 8 + j) * 1024 + lane * 8 + kk * 512);
                acc[0][j] = __builtin_amdgcn_mfma_f32_16x16x32_bf16(a0, b, acc[0][j], 0, 0, 0);
                acc[1][j] = __builtin_amdgcn_mfma_f32_16x16x32_bf16(a1, b, acc[1][j], 0, 0, 0);
            }
        }
    }

#pragma unroll
    for (int mi = 0; mi < 2; ++mi) {
#pragma unroll
        for (int j = 0; j < 8; ++j) {
            const int col = (nw * 8 + j) * 16 + lm;
            const float bc = bb[col];
#pragma unroll
            for (int r = 0; r < 4; ++r) {
                const int row = bm + (2 * mw + mi) * 16 + lq * 4 + r;
                if (row < N_NODES)
                    Hout[(size_t)row * H + col] = f2bf(fmaxf(acc[mi][j][r] + bc, 0.0f));
            }
        }
    }
}

// ---------------------------------------------------------------------------
__global__ __launch_bounds__(256) void pool_kernel(
    const unsigned short* __restrict__ h1, const unsigned short* __restrict__ h2,
    const unsigned short* __restrict__ h3, const int* __restrict__ start,
    float* __restrict__ pool)
{
    const int g = blockIdx.x & 63, layer = blockIdx.x >> 6;
    const unsigned short* h = (layer == 0) ? h1 : (layer == 1) ? h2 : h3;
    const int r0 = start[g], r1 = start[g + 1];
    const int c = threadIdx.x;
    float s0 = 0.f, s1 = 0.f, s2 = 0.f, s3 = 0.f;
    int r = r0;
    for (; r + 4 <= r1; r += 4) {
        s0 += bf2f(h[(size_t)(r + 0) * H + c]);
        s1 += bf2f(h[(size_t)(r + 1) * H + c]);
        s2 += bf2f(h[(size_t)(r + 2) * H + c]);
        s3 += bf2f(h[(size_t)(r + 3) * H + c]);
    }
    for (; r < r1; ++r) s0 += bf2f(h[(size_t)r * H + c]);
    pool[(size_t)g * POOL_W + layer * 256 + c] =
        (s0 + s1 + s2 + s3) / fmaxf((float)(r1 - r0), 1.0f);
}

// ---------------------------------------------------------------------------
__global__ __launch_bounds__(256) void final_kernel(
    const float* __restrict__ pool,
    const float* __restrict__ L1w, const float* __restrict__ L1b,
    const float* __restrict__ L2w, const float* __restrict__ L2b,
    float* __restrict__ out)
{
    const int g = blockIdx.x;
    __shared__ float p[POOL_W];
    __shared__ float f1[POOL_W];
    __shared__ float red[4];

    for (int i = threadIdx.x; i < POOL_W; i += 256)
        p[i] = pool[(size_t)g * POOL_W + i];
    __syncthreads();

    for (int r = 0; r < 3; ++r) {
        const int o = r * 256 + threadIdx.x;
        float acc = L1b[o];
        const float4* wrow = (const float4*)(L1w + (size_t)o * POOL_W);
        for (int k4 = 0; k4 < POOL_W / 4; ++k4) {
            const float4 w4 = wrow[k4];
            acc += w4.x * p[k4 * 4 + 0] + w4.y * p[k4 * 4 + 1]
                 + w4.z * p[k4 * 4 + 2] + w4.w * p[k4 * 4 + 3];
        }
        f1[o] = fmaxf(acc, 0.0f);
    }
    __syncthreads();

    float part = 0.0f;
    for (int i = threadIdx.x; i < POOL_W; i += 256) part += f1[i] * L2w[i];
#pragma unroll
    for (int off = 32; off > 0; off >>= 1) part += __shfl_down(part, off);
    if ((threadIdx.x & 63) == 0) red[threadIdx.x >> 6] = part;
    __syncthreads();
    if (threadIdx.x == 0) {
        const float s = red[0] + red[1] + red[2] + red[3] + L2b[0];
        out[g] = 1.0f / (1.0f + expf(-s));
    }
}

// ---------------------------------------------------------------------------
extern "C" void kernel_launch(void* const* d_in, const int* in_sizes, int n_in,
                              void* d_out, int out_size, void* d_ws, size_t ws_size,
                              hipStream_t stream)
{
    const float* x     = (const float*)d_in[0];
    const float* ea    = (const float*)d_in[1];
    const int*   src   = (const int*)d_in[2];
    const int*   dst   = (const int*)d_in[3];
    const int*   batch = (const int*)d_in[4];

    const float* We[3]; const float* be[3]; const float* Wa[3]; const float* ba[3];
    const float* gg[3]; const float* bt[3]; const float* Wb[3]; const float* bb[3];
    for (int l = 0; l < 3; ++l) {
        const int o = 5 + 8 * l;
        We[l] = (const float*)d_in[o + 0]; be[l] = (const float*)d_in[o + 1];
        Wa[l] = (const float*)d_in[o + 2]; ba[l] = (const float*)d_in[o + 3];
        gg[l] = (const float*)d_in[o + 4]; bt[l] = (const float*)d_in[o + 5];
        Wb[l] = (const float*)d_in[o + 6]; bb[l] = (const float*)d_in[o + 7];
    }
    const float* L1w = (const float*)d_in[29];
    const float* L1b = (const float*)d_in[30];
    const float* L2w = (const float*)d_in[31];
    const float* L2b = (const float*)d_in[32];

    // ---- workspace layout ----
    float* pool   = (float*)d_ws;                              // 64*768
    int*   deg    = (int*)(pool + (size_t)N_GRAPHS * POOL_W);  // N
    int*   off    = deg + N_NODES;                             // N+1
    int*   cursor = off + N_NODES + 1;                         // N
    int*   start  = cursor + N_NODES;                          // 72
    int*   srcS   = start + 72;                                // E
    float* eaS    = (float*)((((uintptr_t)(srcS + N_EDGES)) + 63) & ~(uintptr_t)63);  // E*16
    unsigned short* xb = (unsigned short*)(eaS + (size_t)N_EDGES * 16);
    unsigned short* u  = xb + (size_t)M_PAD * DIN;             // [M_PAD,256] (layer1 uses 128)
    unsigned short* h1 = u  + (size_t)M_PAD * H;
    unsigned short* h2 = h1 + (size_t)M_PAD * H;
    unsigned short* h3 = h2 + (size_t)M_PAD * H;
    unsigned short* wbf[6];
    wbf[0] = h3 + (size_t)M_PAD * H;                           // Wa1 [256,128]
    wbf[1] = wbf[0] + H * DIN;
    for (int i = 2; i < 6; ++i) wbf[i] = wbf[i - 1] + H * H;

    hipMemsetAsync(deg, 0, (size_t)N_NODES * sizeof(int), stream);

    // converts
    cvt_bf<<<(N_NODES * DIN / 4 + 255) / 256, 256, 0, stream>>>(x, xb, N_NODES * DIN / 4);
    for (int l = 0; l < 3; ++l) {
        const int ka = (l == 0) ? DIN : H;
        cvt_bf<<<(H * ka / 4 + 255) / 256, 256, 0, stream>>>(Wa[l], wbf[2 * l], H * ka / 4);
        cvt_bf<<<(H * H  / 4 + 255) / 256, 256, 0, stream>>>(Wb[l], wbf[2 * l + 1], H * H / 4);
    }

    // CSR + graph boundaries
    hist_kernel<<<(N_EDGES + 255) / 256, 256, 0, stream>>>(dst, deg);
    scan_kernel<<<1, 1024, 0, stream>>>(deg, off);
    hipMemcpyAsync(cursor, off, (size_t)N_NODES * sizeof(int),
                   hipMemcpyDeviceToDevice, stream);
    scatter_kernel<<<(N_EDGES + 255) / 256, 256, 0, stream>>>(src, dst, (const float4*)ea,
                                                              cursor, srcS, (float4*)eaS);
    gstart_kernel<<<1, 128, 0, stream>>>(batch, start);

    const int agrid = (N_NODES + 3) / 4;
    const int mgrid = M_PAD / 64;   // 313

    // ---- layer 1 (in=128) ----
    agg5<DIN><<<agrid, 256, 0, stream>>>(xb, eaS, srcS, off, We[0], be[0], u);
    gine_mlp<DIN><<<mgrid, 256, 0, stream>>>(u, wbf[0], ba[0], gg[0], bt[0], wbf[1], bb[0], h1);
    // ---- layer 2 ----
    agg5<H><<<agrid, 256, 0, stream>>>(h1, eaS, srcS, off, We[1], be[1], u);
    gine_mlp<H><<<mgrid, 256, 0, stream>>>(u, wbf[2], ba[1], gg[1], bt[1], wbf[3], bb[1], h2);
    // ---- layer 3 ----
    agg5<H><<<agrid, 256, 0, stream>>>(h2, eaS, srcS, off, We[2], be[2], u);
    gine_mlp<H><<<mgrid, 256, 0, stream>>>(u, wbf[4], ba[2], gg[2], bt[2], wbf[5], bb[2], h3);

    // pooling + head
    pool_kernel<<<3 * N_GRAPHS, 256, 0, stream>>>(h1, h2, h3, start, pool);
    final_kernel<<<N_GRAPHS, 256, 0, stream>>>(pool, L1w, L1b, L2w, L2b, (float*)d_out);
}

// Round 8
// 638.852 us; speedup vs baseline: 2.3659x; 1.0700x over previous
//
#include <hip/hip_runtime.h>
#include <math.h>
#include <stdint.h>

#define N_NODES 20000
#define M_PAD 20032            // 313 * 64
#define N_EDGES 320000
#define N_GRAPHS 64
#define DIN 128
#define H 256
#define POOL_W 768

typedef __attribute__((ext_vector_type(8))) short bf16x8;   // 8 bf16 = 4 VGPRs
typedef __attribute__((ext_vector_type(4))) float f32x4;

__device__ __forceinline__ unsigned short f2bf(float f) {
    unsigned u = __builtin_bit_cast(unsigned, f);
    u += 0x7FFFu + ((u >> 16) & 1u);          // round-to-nearest-even
    return (unsigned short)(u >> 16);
}
__device__ __forceinline__ float bf2f(unsigned short u) {
    return __builtin_bit_cast(float, (unsigned)u << 16);
}

// ---------------------------------------------------------------------------
// CSR build
// ---------------------------------------------------------------------------
__global__ __launch_bounds__(256) void hist_kernel(const int* __restrict__ dst,
                                                   int* __restrict__ deg)
{
    const int i = blockIdx.x * 256 + threadIdx.x;
    if (i < N_EDGES) atomicAdd(deg + dst[i], 1);
}

// shfl scan; writes both off and cursor (saves a d2d copy launch)
__global__ __launch_bounds__(1024) void scan_kernel(const int* __restrict__ deg,
                                                    int* __restrict__ off,
                                                    int* __restrict__ cur)
{
    __shared__ int wsum[16];
    __shared__ int carry;
    const int tid = threadIdx.x, wave = tid >> 6, lane = tid & 63;
    if (tid == 0) carry = 0;
    __syncthreads();
    for (int base = 0; base < N_NODES; base += 1024) {
        const int i = base + tid;
        const int v = (i < N_NODES) ? deg[i] : 0;
        int s = v;
#pragma unroll
        for (int d = 1; d < 64; d <<= 1) {
            const int t = __shfl_up(s, d);
            if (lane >= d) s += t;
        }
        if (lane == 63) wsum[wave] = s;
        __syncthreads();
        if (wave == 0) {
            int t = (lane < 16) ? wsum[lane] : 0;
#pragma unroll
            for (int d = 1; d < 16; d <<= 1) {
                const int u = __shfl_up(t, d);
                if (lane >= d) t += u;
            }
            if (lane < 16) wsum[lane] = t;
        }
        __syncthreads();
        const int wbase = (wave == 0) ? 0 : wsum[wave - 1];
        if (i < N_NODES) {
            const int o = carry + wbase + s - v;
            off[i] = o;
            cur[i] = o;
        }
        const int tot = wsum[15];
        __syncthreads();
        if (tid == 0) carry += tot;
        __syncthreads();
    }
    if (tid == 0) off[N_NODES] = carry;
}

// scatter edge payload into dst-sorted order: src id + full 64B ea row
__global__ __launch_bounds__(256) void scatter_kernel(
    const int* __restrict__ src, const int* __restrict__ dst,
    const float4* __restrict__ ea4,
    int* __restrict__ cursor, int* __restrict__ srcS, float4* __restrict__ eaS4)
{
    const int e = blockIdx.x * 256 + threadIdx.x;
    if (e < N_EDGES) {
        const int p = atomicAdd(cursor + dst[e], 1);
        srcS[p] = src[e];
        const float4 a = ea4[e * 4 + 0], b = ea4[e * 4 + 1];
        const float4 c = ea4[e * 4 + 2], d = ea4[e * 4 + 3];
        eaS4[p * 4 + 0] = a; eaS4[p * 4 + 1] = b;
        eaS4[p * 4 + 2] = c; eaS4[p * 4 + 3] = d;
    }
}

__global__ void gstart_kernel(const int* __restrict__ batch, int* __restrict__ start)
{
    const int g = threadIdx.x;
    if (g > N_GRAPHS) return;
    if (g == N_GRAPHS) { start[N_GRAPHS] = N_NODES; return; }
    int lo = 0, hi = N_NODES;
    while (lo < hi) { const int mid = (lo + hi) >> 1; if (batch[mid] < g) lo = mid + 1; else hi = mid; }
    start[g] = lo;
}

// ---------------------------------------------------------------------------
// Batched fp32 -> bf16 converts: 7 jobs in one launch (grid.y = job)
// ---------------------------------------------------------------------------
struct CvtJob  { const float* s; unsigned short* d; int n4; };
struct CvtJobs { CvtJob j[7]; };

__global__ __launch_bounds__(256) void cvt_all(CvtJobs jobs)
{
    const CvtJob J = jobs.j[blockIdx.y];
    for (int i = blockIdx.x * 256 + threadIdx.x; i < J.n4; i += gridDim.x * 256) {
        const float4 v = ((const float4*)J.s)[i];
        ushort4 r;
        r.x = f2bf(v.x); r.y = f2bf(v.y); r.z = f2bf(v.z); r.w = f2bf(v.w);
        ((ushort4*)J.d)[i] = r;
    }
}

// ---------------------------------------------------------------------------
// agg v5 (unchanged, proven 96 us): one wave/node, ea via SGPR scalar loads.
// out[v] = bf16( x[v] + sum_e relu(x[src] + ea@We.T + be) )
// ---------------------------------------------------------------------------
template<int IN>
__global__ __launch_bounds__(256, 4) void agg5(
    const unsigned short* __restrict__ xb,   // [M_PAD, IN] bf16
    const float* __restrict__ eaS,           // [E,16] fp32, dst-sorted
    const int* __restrict__ srcS,            // [E] dst-sorted
    const int* __restrict__ off,             // [N+1]
    const float* __restrict__ We, const float* __restrict__ be,
    unsigned short* __restrict__ out)        // [M_PAD, IN] bf16
{
    constexpr int CPL = IN / 64;             // 2 (layer1) or 4
    const int lane = threadIdx.x & 63;
    const int node = blockIdx.x * 4 + (threadIdx.x >> 6);
    if (node >= N_NODES) return;
    const int c0 = lane * CPL;

    float w[CPL][16], bias[CPL], acc[CPL];
#pragma unroll
    for (int j = 0; j < CPL; ++j) {
        bias[j] = be[c0 + j];
        acc[j]  = 0.0f;
#pragma unroll
        for (int k = 0; k < 16; ++k) w[j][k] = We[(c0 + j) * 16 + k];
    }

    const int p0 = __builtin_amdgcn_readfirstlane(off[node]);
    const int p1 = __builtin_amdgcn_readfirstlane(off[node + 1]);

    float  en[16];
    ushort4 xn = {0, 0, 0, 0};
    if (p0 < p1) {
        const int s = __builtin_amdgcn_readfirstlane(srcS[p0]);
        const float* er = eaS + (size_t)p0 * 16;
#pragma unroll
        for (int k = 0; k < 16; ++k) en[k] = er[k];
        if (CPL == 4) xn = *(const ushort4*)(xb + (size_t)s * IN + c0);
        else { const ushort2 t2 = *(const ushort2*)(xb + (size_t)s * IN + c0); xn.x = t2.x; xn.y = t2.y; }
    }

    for (int p = p0; p < p1; ++p) {
        float ec[16];
#pragma unroll
        for (int k = 0; k < 16; ++k) ec[k] = en[k];
        const ushort4 xc = xn;
        if (p + 1 < p1) {
            const int s = __builtin_amdgcn_readfirstlane(srcS[p + 1]);
            const float* er = eaS + (size_t)(p + 1) * 16;
#pragma unroll
            for (int k = 0; k < 16; ++k) en[k] = er[k];
            if (CPL == 4) xn = *(const ushort4*)(xb + (size_t)s * IN + c0);
            else { const ushort2 t2 = *(const ushort2*)(xb + (size_t)s * IN + c0); xn.x = t2.x; xn.y = t2.y; }
        }
        float m[CPL];
#pragma unroll
        for (int j = 0; j < CPL; ++j) m[j] = bias[j];
#pragma unroll
        for (int k = 0; k < 16; ++k)
#pragma unroll
            for (int j = 0; j < CPL; ++j) m[j] = fmaf(ec[k], w[j][k], m[j]);
#pragma unroll
        for (int j = 0; j < CPL; ++j) {
            const float v = m[j] + bf2f((&xc.x)[j]);
            acc[j] += fmaxf(v, 0.0f);
        }
    }

    if (CPL == 4) {
        const ushort4 xs = *(const ushort4*)(xb + (size_t)node * IN + c0);
        ushort4 o;
#pragma unroll
        for (int j = 0; j < 4; ++j) (&o.x)[j] = f2bf(bf2f((&xs.x)[j]) + acc[j]);
        *(ushort4*)(out + (size_t)node * IN + c0) = o;
    } else {
        const ushort2 xs = *(const ushort2*)(xb + (size_t)node * IN + c0);
        ushort2 o;
        o.x = f2bf(bf2f(xs.x) + acc[0]);
        o.y = f2bf(bf2f(xs.y) + acc[1]);
        *(ushort2*)(out + (size_t)node * IN + c0) = o;
    }
}

// ---------------------------------------------------------------------------
// B-in-register streaming GEMM: C[M_PAD,256] = epi(A[M_PAD,K] @ W[256,K]^T)
// grid (M_PAD/64, 2), block = 4 waves. Wave owns 32 cols (2 16-col tiles)
// with its full B-slice in VGPRs (K/32 chunks x 2 tiles x bf16x8), loops
// over 4 chunks of 16 rows streaming A straight from global (no LDS).
// EPI 0: BN(eval)+relu -> bf16 (all M_PAD rows)
// EPI 1: bias+relu -> bf16 (rows < N_NODES)
// ---------------------------------------------------------------------------
template<int K, int EPI>
__global__ __launch_bounds__(256) void gemm_breg(
    const unsigned short* __restrict__ A,    // [M_PAD, K]
    const unsigned short* __restrict__ W,    // [256, K]
    const float* __restrict__ bias,
    const float* __restrict__ gsc, const float* __restrict__ bsh,
    unsigned short* __restrict__ out)        // [M_PAD, 256]
{
    constexpr int KC = K / 32;               // 4 or 8 k-chunks
    const int w = threadIdx.x >> 6, lane = threadIdx.x & 63;
    const int lm = lane & 15, lq = lane >> 4;
    const int n0 = (blockIdx.y * 4 + w) * 32;
    const int m0 = blockIdx.x * 64;

    // B resident in registers
    bf16x8 B0[KC], B1[KC];
    {
        const unsigned short* Wp0 = W + (size_t)(n0 + lm) * K + lq * 8;
        const unsigned short* Wp1 = W + (size_t)(n0 + 16 + lm) * K + lq * 8;
#pragma unroll
        for (int c = 0; c < KC; ++c) {
            B0[c] = *(const bf16x8*)(Wp0 + c * 32);
            B1[c] = *(const bf16x8*)(Wp1 + c * 32);
        }
    }

    const float inv = rsqrtf(1.0f + 1e-5f);
    const float bc0 = bias[n0 + lm],      bc1 = bias[n0 + 16 + lm];
    const float gc0 = (EPI == 0) ? gsc[n0 + lm]      : 0.0f;
    const float gc1 = (EPI == 0) ? gsc[n0 + 16 + lm] : 0.0f;
    const float sc0 = (EPI == 0) ? bsh[n0 + lm]      : 0.0f;
    const float sc1 = (EPI == 0) ? bsh[n0 + 16 + lm] : 0.0f;

#pragma unroll
    for (int ch = 0; ch < 4; ++ch) {
        const int mr = m0 + ch * 16;
        const unsigned short* Ap = A + (size_t)(mr + lm) * K + lq * 8;
        bf16x8 a[KC];
#pragma unroll
        for (int c = 0; c < KC; ++c) a[c] = *(const bf16x8*)(Ap + c * 32);

        f32x4 acc0 = (f32x4){0.f, 0.f, 0.f, 0.f};
        f32x4 acc1 = (f32x4){0.f, 0.f, 0.f, 0.f};
#pragma unroll
        for (int c = 0; c < KC; ++c) {
            acc0 = __builtin_amdgcn_mfma_f32_16x16x32_bf16(a[c], B0[c], acc0, 0, 0, 0);
            acc1 = __builtin_amdgcn_mfma_f32_16x16x32_bf16(a[c], B1[c], acc1, 0, 0, 0);
        }

#pragma unroll
        for (int r = 0; r < 4; ++r) {
            const int row = mr + lq * 4 + r;
            if (EPI == 1 && row >= N_NODES) continue;
            float v0 = acc0[r] + bc0;
            float v1 = acc1[r] + bc1;
            if (EPI == 0) {
                v0 = fmaxf(v0 * inv * gc0 + sc0, 0.0f);
                v1 = fmaxf(v1 * inv * gc1 + sc1, 0.0f);
            } else {
                v0 = fmaxf(v0, 0.0f);
                v1 = fmaxf(v1, 0.0f);
            }
            out[(size_t)row * H + n0 + lm]      = f2bf(v0);
            out[(size_t)row * H + n0 + 16 + lm] = f2bf(v1);
        }
    }
}

// ---------------------------------------------------------------------------
__global__ __launch_bounds__(256) void pool_kernel(
    const unsigned short* __restrict__ h1, const unsigned short* __restrict__ h2,
    const unsigned short* __restrict__ h3, const int* __restrict__ start,
    float* __restrict__ pool)
{
    const int g = blockIdx.x & 63, layer = blockIdx.x >> 6;
    const unsigned short* h = (layer == 0) ? h1 : (layer == 1) ? h2 : h3;
    const int r0 = start[g], r1 = start[g + 1];
    const int c = threadIdx.x;
    float s0 = 0.f, s1 = 0.f, s2 = 0.f, s3 = 0.f;
    int r = r0;
    for (; r + 4 <= r1; r += 4) {
        s0 += bf2f(h[(size_t)(r + 0) * H + c]);
        s1 += bf2f(h[(size_t)(r + 1) * H + c]);
        s2 += bf2f(h[(size_t)(r + 2) * H + c]);
        s3 += bf2f(h[(size_t)(r + 3) * H + c]);
    }
    for (; r < r1; ++r) s0 += bf2f(h[(size_t)r * H + c]);
    pool[(size_t)g * POOL_W + layer * 256 + c] =
        (s0 + s1 + s2 + s3) / fmaxf((float)(r1 - r0), 1.0f);
}

// ---------------------------------------------------------------------------
__global__ __launch_bounds__(256) void final_kernel(
    const float* __restrict__ pool,
    const float* __restrict__ L1w, const float* __restrict__ L1b,
    const float* __restrict__ L2w, const float* __restrict__ L2b,
    float* __restrict__ out)
{
    const int g = blockIdx.x;
    __shared__ float p[POOL_W];
    __shared__ float f1[POOL_W];
    __shared__ float red[4];

    for (int i = threadIdx.x; i < POOL_W; i += 256)
        p[i] = pool[(size_t)g * POOL_W + i];
    __syncthreads();

    for (int r = 0; r < 3; ++r) {
        const int o = r * 256 + threadIdx.x;
        float acc = L1b[o];
        const float4* wrow = (const float4*)(L1w + (size_t)o * POOL_W);
        for (int k4 = 0; k4 < POOL_W / 4; ++k4) {
            const float4 w4 = wrow[k4];
            acc += w4.x * p[k4 * 4 + 0] + w4.y * p[k4 * 4 + 1]
                 + w4.z * p[k4 * 4 + 2] + w4.w * p[k4 * 4 + 3];
        }
        f1[o] = fmaxf(acc, 0.0f);
    }
    __syncthreads();

    float part = 0.0f;
    for (int i = threadIdx.x; i < POOL_W; i += 256) part += f1[i] * L2w[i];
#pragma unroll
    for (int off = 32; off > 0; off >>= 1) part += __shfl_down(part, off);
    if ((threadIdx.x & 63) == 0) red[threadIdx.x >> 6] = part;
    __syncthreads();
    if (threadIdx.x == 0) {
        const float s = red[0] + red[1] + red[2] + red[3] + L2b[0];
        out[g] = 1.0f / (1.0f + expf(-s));
    }
}

// ---------------------------------------------------------------------------
extern "C" void kernel_launch(void* const* d_in, const int* in_sizes, int n_in,
                              void* d_out, int out_size, void* d_ws, size_t ws_size,
                              hipStream_t stream)
{
    const float* x     = (const float*)d_in[0];
    const float* ea    = (const float*)d_in[1];
    const int*   src   = (const int*)d_in[2];
    const int*   dst   = (const int*)d_in[3];
    const int*   batch = (const int*)d_in[4];

    const float* We[3]; const float* be[3]; const float* Wa[3]; const float* ba[3];
    const float* gg[3]; const float* bt[3]; const float* Wb[3]; const float* bb[3];
    for (int l = 0; l < 3; ++l) {
        const int o = 5 + 8 * l;
        We[l] = (const float*)d_in[o + 0]; be[l] = (const float*)d_in[o + 1];
        Wa[l] = (const float*)d_in[o + 2]; ba[l] = (const float*)d_in[o + 3];
        gg[l] = (const float*)d_in[o + 4]; bt[l] = (const float*)d_in[o + 5];
        Wb[l] = (const float*)d_in[o + 6]; bb[l] = (const float*)d_in[o + 7];
    }
    const float* L1w = (const float*)d_in[29];
    const float* L1b = (const float*)d_in[30];
    const float* L2w = (const float*)d_in[31];
    const float* L2b = (const float*)d_in[32];

    // ---- workspace layout ----
    float* pool   = (float*)d_ws;                              // 64*768
    int*   deg    = (int*)(pool + (size_t)N_GRAPHS * POOL_W);  // N
    int*   off    = deg + N_NODES;                             // N+1
    int*   cursor = off + N_NODES + 1;                         // N
    int*   start  = cursor + N_NODES;                          // 72
    int*   srcS   = start + 72;                                // E
    float* eaS    = (float*)((((uintptr_t)(srcS + N_EDGES)) + 63) & ~(uintptr_t)63);  // E*16
    unsigned short* xb = (unsigned short*)(eaS + (size_t)N_EDGES * 16);
    unsigned short* u  = xb + (size_t)M_PAD * DIN;             // [M_PAD,256] (layer1 uses 128)
    unsigned short* tT = u  + (size_t)M_PAD * H;               // [M_PAD,256] intermediate
    unsigned short* h1 = tT + (size_t)M_PAD * H;
    unsigned short* h2 = h1 + (size_t)M_PAD * H;
    unsigned short* h3 = h2 + (size_t)M_PAD * H;
    unsigned short* wbf[6];
    wbf[0] = h3 + (size_t)M_PAD * H;                           // Wa1 [256,128]
    wbf[1] = wbf[0] + H * DIN;
    for (int i = 2; i < 6; ++i) wbf[i] = wbf[i - 1] + H * H;

    hipMemsetAsync(deg, 0, (size_t)N_NODES * sizeof(int), stream);

    // batched converts: x + 6 weights in one launch
    CvtJobs jobs;
    jobs.j[0] = { x,     xb,     N_NODES * DIN / 4 };
    jobs.j[1] = { Wa[0], wbf[0], H * DIN / 4 };
    jobs.j[2] = { Wb[0], wbf[1], H * H / 4 };
    jobs.j[3] = { Wa[1], wbf[2], H * H / 4 };
    jobs.j[4] = { Wb[1], wbf[3], H * H / 4 };
    jobs.j[5] = { Wa[2], wbf[4], H * H / 4 };
    jobs.j[6] = { Wb[2], wbf[5], H * H / 4 };
    cvt_all<<<dim3(320, 7), 256, 0, stream>>>(jobs);

    // CSR + graph boundaries
    hist_kernel<<<(N_EDGES + 255) / 256, 256, 0, stream>>>(dst, deg);
    scan_kernel<<<1, 1024, 0, stream>>>(deg, off, cursor);
    scatter_kernel<<<(N_EDGES + 255) / 256, 256, 0, stream>>>(src, dst, (const float4*)ea,
                                                              cursor, srcS, (float4*)eaS);
    gstart_kernel<<<1, 128, 0, stream>>>(batch, start);

    const int  agrid = (N_NODES + 3) / 4;
    const dim3 ggrid(M_PAD / 64, 2);   // (313, 2)

    // ---- layer 1 (in=128) ----
    agg5<DIN><<<agrid, 256, 0, stream>>>(xb, eaS, srcS, off, We[0], be[0], u);
    gemm_breg<DIN, 0><<<ggrid, 256, 0, stream>>>(u, wbf[0], ba[0], gg[0], bt[0], tT);
    gemm_breg<H,   1><<<ggrid, 256, 0, stream>>>(tT, wbf[1], bb[0], nullptr, nullptr, h1);
    // ---- layer 2 ----
    agg5<H><<<agrid, 256, 0, stream>>>(h1, eaS, srcS, off, We[1], be[1], u);
    gemm_breg<H, 0><<<ggrid, 256, 0, stream>>>(u, wbf[2], ba[1], gg[1], bt[1], tT);
    gemm_breg<H, 1><<<ggrid, 256, 0, stream>>>(tT, wbf[3], bb[1], nullptr, nullptr, h2);
    // ---- layer 3 ----
    agg5<H><<<agrid, 256, 0, stream>>>(h2, eaS, srcS, off, We[2], be[2], u);
    gemm_breg<H, 0><<<ggrid, 256, 0, stream>>>(u, wbf[4], ba[2], gg[2], bt[2], tT);
    gemm_breg<H, 1><<<ggrid, 256, 0, stream>>>(tT, wbf[5], bb[2], nullptr, nullptr, h3);

    // pooling + head
    pool_kernel<<<3 * N_GRAPHS, 256, 0, stream>>>(h1, h2, h3, start, pool);
    final_kernel<<<N_GRAPHS, 256, 0, stream>>>(pool, L1w, L1b, L2w, L2b, (float*)d_out);
}